// Round 1
// baseline (18973.099 us; speedup 1.0000x reference)
//
#include <hip/hip_runtime.h>

// ---------------------------------------------------------------------------
// GRU forecaster: B=32, T=2048, I=256, H=512, L=2, O=64   (f16 datapath)
// Scan: 8 clusters x 8 WGs (64 WGs total), each cluster owns 4 BATCHES
// interleaved per step (weights in VGPRs are shared across batches, so the
// 4 independent recurrences hide the cross-CU h-exchange latency).
// cluster = wg & 7 -> XCD-local exchange under round-robin dispatch.
// h exchanged as u32 {epoch<<16|f16} agent-scope atomics; LDS h buffer
// XOR-swizzled (conflict-free ds_read_b128). One barrier per 4 batch-steps.
// ---------------------------------------------------------------------------

typedef unsigned int  u32;
typedef unsigned short u16;
typedef float v4f __attribute__((ext_vector_type(4)));
typedef _Float16 v2h __attribute__((ext_vector_type(2)));
typedef _Float16 v8h __attribute__((ext_vector_type(8)));

#if defined(__has_builtin)
#  if __has_builtin(__builtin_amdgcn_fdot2)
#    define FDOT2(a, b, c) __builtin_amdgcn_fdot2((a), (b), (c), false)
#  endif
#endif
#ifndef FDOT2
#  define FDOT2(a, b, c) ((c) + (float)(a)[0] * (float)(b)[0] + (float)(a)[1] * (float)(b)[1])
#endif

__device__ __forceinline__ u16 f2h(float f) {
    _Float16 h = (_Float16)f;
    return *(u16*)&h;
}
__device__ __forceinline__ float h2f(u16 b) {
    _Float16 h = *(_Float16*)&b;
    return (float)h;
}

// --------------------------- prep kernels ----------------------------------

// src fp32 [R][C] -> dst f16 [C][R]  (32x32 tiles)
__global__ __launch_bounds__(256) void transpose_cast(const float* __restrict__ src,
                                                      u16* __restrict__ dst,
                                                      int R, int C) {
    __shared__ u16 tile[32][33];
    int c0 = blockIdx.x * 32, r0 = blockIdx.y * 32;
    int t = threadIdx.x;
    {
        int rl = t >> 3, cl4 = (t & 7) * 4;
        float4 v = *(const float4*)&src[(size_t)(r0 + rl) * C + c0 + cl4];
        tile[rl][cl4 + 0] = f2h(v.x);
        tile[rl][cl4 + 1] = f2h(v.y);
        tile[rl][cl4 + 2] = f2h(v.z);
        tile[rl][cl4 + 3] = f2h(v.w);
    }
    __syncthreads();
    {
        int cl = t >> 3, rl4 = (t & 7) * 4;
        uint2 o;
        o.x = (u32)tile[rl4 + 0][cl] | ((u32)tile[rl4 + 1][cl] << 16);
        o.y = (u32)tile[rl4 + 2][cl] | ((u32)tile[rl4 + 3][cl] << 16);
        *(uint2*)&dst[(size_t)(c0 + cl) * R + r0 + rl4] = o;
    }
}

// Wh fp32 [512][1536] -> f16 regs layout: uint4 index ((m*8+w)*24 + c)*64 + lane,
// lane = kseg*8+jb, c = g*8+qk; holds Wh[k = kseg*64+qk*8+i][g*512 + m*64+w*8+jb].
__global__ __launch_bounds__(256) void pack_wh(const float* __restrict__ Wh,
                                               uint4* __restrict__ dst) {
    int id = blockIdx.x * 256 + threadIdx.x;   // < 98304
    int lane = id & 63;
    int c = (id >> 6) % 24;
    int mw = id / 1536;                        // m*8 + w
    int kseg = lane >> 3, jb = lane & 7;
    int g = c >> 3, qk = c & 7;
    int col = g * 512 + (mw >> 3) * 64 + (mw & 7) * 8 + jb;
    int kb = kseg * 64 + qk * 8;
    u32 d[4];
#pragma unroll
    for (int p = 0; p < 4; ++p) {
        u16 a = f2h(Wh[(size_t)(kb + 2 * p) * 1536 + col]);
        u16 b = f2h(Wh[(size_t)(kb + 2 * p + 1) * 1536 + col]);
        d[p] = (u32)a | ((u32)b << 16);
    }
    uint4 o; o.x = d[0]; o.y = d[1]; o.z = d[2]; o.w = d[3];
    dst[id] = o;
}

// ---------------- GEMM: xi_chunk = A_rows @ Bt^T + bias -> f16 --------------
template <int K, bool AF32>
__global__ __launch_bounds__(256) void gemm_xi(const void* __restrict__ Ap,
                                               const u16* __restrict__ Bt,
                                               const float* __restrict__ bias,
                                               u16* __restrict__ C,
                                               int t0, int lgTc) {
    __shared__ u16 As[64 * 40];
    __shared__ u16 Bs[64 * 40];
    const int tid = threadIdx.x;
    const int n0 = blockIdx.x * 64;
    const int m0 = blockIdx.y * 64;
    const int row = tid >> 2, koff = (tid & 3) * 8;
    const int lane = tid & 63, w = tid >> 6;
    const int m = m0 + row;
    const int b = m >> lgTc;
    const int tl = m & ((1 << lgTc) - 1);
    const size_t srow = ((size_t)b << 11) + (size_t)(t0 + tl);
    v4f acc[4];
#pragma unroll
    for (int i = 0; i < 4; ++i) acc[i] = (v4f){0.f, 0.f, 0.f, 0.f};

    for (int k0 = 0; k0 < K; k0 += 32) {
        if (AF32) {
            const float* A = (const float*)Ap;
            float4 v0 = *(const float4*)&A[srow * K + k0 + koff];
            float4 v1 = *(const float4*)&A[srow * K + k0 + koff + 4];
            uint4 o;
            o.x = (u32)f2h(v0.x) | ((u32)f2h(v0.y) << 16);
            o.y = (u32)f2h(v0.z) | ((u32)f2h(v0.w) << 16);
            o.z = (u32)f2h(v1.x) | ((u32)f2h(v1.y) << 16);
            o.w = (u32)f2h(v1.z) | ((u32)f2h(v1.w) << 16);
            *(uint4*)&As[row * 40 + koff] = o;
        } else {
            const u16* A = (const u16*)Ap;
            *(uint4*)&As[row * 40 + koff] =
                *(const uint4*)&A[srow * K + k0 + koff];
        }
        *(uint4*)&Bs[row * 40 + koff] =
            *(const uint4*)&Bt[(size_t)(n0 + row) * K + k0 + koff];
        __syncthreads();
        v8h a = *(const v8h*)&As[(w * 16 + (lane & 15)) * 40 + (lane >> 4) * 8];
#pragma unroll
        for (int nt = 0; nt < 4; ++nt) {
            v8h bm = *(const v8h*)&Bs[(nt * 16 + (lane & 15)) * 40 + (lane >> 4) * 8];
            acc[nt] = __builtin_amdgcn_mfma_f32_16x16x32_f16(a, bm, acc[nt], 0, 0, 0);
        }
        __syncthreads();
    }
#pragma unroll
    for (int nt = 0; nt < 4; ++nt) {
        int col = n0 + nt * 16 + (lane & 15);
        float bv = bias[col];
#pragma unroll
        for (int rI = 0; rI < 4; ++rI) {
            int rowm = m0 + w * 16 + (lane >> 4) * 4 + rI;
            C[(size_t)rowm * 1536 + col] = f2h(acc[nt][rI] + bv);
        }
    }
}

// --------------------------- GRU scan (cooperative) -------------------------
// grid = 64 x 512. cluster = wg & 7 (XCD-local), member = wg >> 3.
// Cluster owns batches bg = cluster*4 + q, q = 0..3 (interleaved per step).
// Member owns j in [member*64, +64). Thread (w, lane): kseg = lane>>3 covers
// k in [kseg*64,+64), jb = lane&7, j = member*64 + w*8 + jb.
// Weights in VGPRs (shared across the 4 batches!). h in LDS, XOR-swizzled.
__global__ __launch_bounds__(512, 2) void gru_scan(const u16* __restrict__ xi,
                                                   const uint4* __restrict__ Whp,
                                                   const float* __restrict__ bhn,
                                                   u32* __restrict__ Hb,
                                                   u16* __restrict__ hseq,
                                                   float* __restrict__ h1last,
                                                   float* __restrict__ hstate,
                                                   int t0, int Tc, int layer0) {
    __shared__ __align__(16) u16 Lhh[4][2][512];

    const int tid = threadIdx.x;
    const int wg = blockIdx.x;
    const int cluster = wg & 7;           // one cluster per XCD (wg%8 RR)
    const int member = wg >> 3;           // 8 members per cluster
    const int w = tid >> 6, lane = tid & 63;
    const int kseg = lane >> 3, jb = lane & 7;
    const int j = member * 64 + w * 8 + jb;
    const bool fin = (kseg == 0);

    // weights -> VGPRs (coalesced: per c, 64 lanes read 1KB contiguous)
    uint4 Wreg[24];
    {
        const uint4* src = Whp + ((size_t)(member * 8 + w) * 24) * 64 + lane;
#pragma unroll
        for (int c = 0; c < 24; ++c) Wreg[c] = src[c * 64];
    }

    // swizzled write index for k = tid (loop-invariant)
    const int pks = tid >> 6, pqk = (tid >> 3) & 7, pi = tid & 7;
    const int physw = (pks * 8 + (pqk ^ pks)) * 8 + pi;

    float hprev[4];
    u16 rx[4], rz[4], rn[4];
    float bhnv = 0.f;
    if (fin) bhnv = bhn[j];

#pragma unroll
    for (int q = 0; q < 4; ++q) {
        const int bg = cluster * 4 + q;
        u32 v = 0;
        if (t0 > 0)
            v = __hip_atomic_load(&Hb[(size_t)bg * 1024 + ((t0 - 1) & 1) * 512 + tid],
                                  __ATOMIC_RELAXED, __HIP_MEMORY_SCOPE_AGENT);
        Lhh[q][t0 & 1][physw] = (u16)v;
        hprev[q] = 0.f; rx[q] = 0; rz[q] = 0; rn[q] = 0;
        if (fin) {
            if (t0 > 0) hprev[q] = hstate[bg * 512 + j];
            const u16* p = xi + (size_t)bg * Tc * 1536 + j;
            rx[q] = p[0]; rz[q] = p[512]; rn[q] = p[1024];
        }
    }
    __syncthreads();

    for (int t = t0; t < t0 + Tc; ++t) {
        // ---- phase 1: per batch, dots -> reduce -> activate -> store ------
#pragma unroll
        for (int q = 0; q < 4; ++q) {
            const int bg = cluster * 4 + q;
            const u16* lhp = Lhh[q][t & 1];
            float a0 = 0.f, a1 = 0.f, a2 = 0.f;
#pragma unroll
            for (int qk = 0; qk < 8; ++qk) {
                v8h h8 = *(const v8h*)&lhp[(kseg * 8 + (qk ^ kseg)) * 8];
                const v2h* hp = (const v2h*)&h8;
                v8h w0 = *(const v8h*)&Wreg[qk];
                v8h w1 = *(const v8h*)&Wreg[8 + qk];
                v8h w2 = *(const v8h*)&Wreg[16 + qk];
                const v2h* p0 = (const v2h*)&w0;
                const v2h* p1 = (const v2h*)&w1;
                const v2h* p2 = (const v2h*)&w2;
#pragma unroll
                for (int p = 0; p < 4; ++p) {
                    a0 = FDOT2(p0[p], hp[p], a0);
                    a1 = FDOT2(p1[p], hp[p], a1);
                    a2 = FDOT2(p2[p], hp[p], a2);
                }
            }
            // reduce over kseg (lane bits 3,4,5)
#pragma unroll
            for (int d = 8; d <= 32; d <<= 1) {
                a0 += __shfl_xor(a0, d);
                a1 += __shfl_xor(a1, d);
                a2 += __shfl_xor(a2, d);
            }
            if (fin) {
                float r = 1.f / (1.f + __expf(-(h2f(rx[q]) + a0)));
                float z = 1.f / (1.f + __expf(-(h2f(rz[q]) + a1)));
                float nx = h2f(rn[q]) + r * (a2 + bhnv);
                float n = 1.f - 2.f / (__expf(2.f * nx) + 1.f);   // tanh
                float hn = (1.f - z) * n + z * hprev[q];
                hprev[q] = hn;
                u16 hh = f2h(hn);
                u32* slot = Hb + (size_t)bg * 1024 + (size_t)(t & 1) * 512;
                __hip_atomic_store(&slot[j], ((u32)(u16)(t + 1) << 16) | (u32)hh,
                                   __ATOMIC_RELAXED, __HIP_MEMORY_SCOPE_AGENT);
                if (layer0) hseq[((size_t)bg * 2048 + t) * 512 + j] = hh;
                if (!layer0 && t == 2047) h1last[bg * 512 + j] = hn;
                if (t + 1 < t0 + Tc) {   // prefetch xi for t+1
                    const u16* p = xi + ((size_t)bg * Tc + (t + 1 - t0)) * 1536 + j;
                    rx[q] = p[0]; rz[q] = p[512]; rn[q] = p[1024];
                }
            }
        }
        // ---- phase 2: per batch, poll own u32 & fill next parity buffer ---
#pragma unroll
        for (int q = 0; q < 4; ++q) {
            const int bg = cluster * 4 + q;
            const u32 target = (u32)(u16)(t + 1) << 16;
            u32* myq = Hb + (size_t)bg * 1024 + (size_t)(t & 1) * 512 + tid;
            u32 qv = 0;
            for (int it = 0; it < 4000000; ++it) {
                qv = __hip_atomic_load(myq, __ATOMIC_RELAXED, __HIP_MEMORY_SCOPE_AGENT);
                if ((qv & 0xFFFF0000u) == target) break;
                if (it > 4) __builtin_amdgcn_s_sleep(1);
            }
            Lhh[q][(t + 1) & 1][physw] = (u16)qv;
        }
        __syncthreads();
    }
    if (fin) {
#pragma unroll
        for (int q = 0; q < 4; ++q) hstate[(cluster * 4 + q) * 512 + j] = hprev[q];
    }
}

// --------------------------- final FC --------------------------------------
__global__ __launch_bounds__(64) void final_fc(const float* __restrict__ h1,
                                               const float* __restrict__ Wfc,
                                               const float* __restrict__ bfc,
                                               float* __restrict__ out) {
    int b = blockIdx.x, o = threadIdx.x;
    float acc = bfc[o];
    for (int k = 0; k < 512; ++k) acc += h1[b * 512 + k] * Wfc[k * 64 + o];
    out[b * 64 + o] = acc;
}

// --------------------------- launch ----------------------------------------

extern "C" void kernel_launch(void* const* d_in, const int* in_sizes, int n_in,
                              void* d_out, int out_size, void* d_ws, size_t ws_size,
                              hipStream_t stream) {
    const float* x    = (const float*)d_in[0];
    const float* Wi0  = (const float*)d_in[1];
    const float* bi0  = (const float*)d_in[2];
    const float* Wh0  = (const float*)d_in[3];
    const float* bhn0 = (const float*)d_in[4];
    const float* Wi1  = (const float*)d_in[5];
    const float* bi1  = (const float*)d_in[6];
    const float* Wh1  = (const float*)d_in[7];
    const float* bhn1 = (const float*)d_in[8];
    const float* Wfc  = (const float*)d_in[9];
    const float* bfc  = (const float*)d_in[10];
    float* out = (float*)d_out;
    (void)in_sizes; (void)n_in; (void)out_size;

    char* ws = (char*)d_ws;
    size_t off = 0;
    auto take = [&](size_t bytes) -> char* {
        char* p = ws + off;
        off = (off + bytes + 255) & ~(size_t)255;
        return p;
    };
    u16*  Wi0t  = (u16*)take(1536 * 256 * 2);
    u16*  Wi1t  = (u16*)take(1536 * 512 * 2);
    uint4* Wh0p = (uint4*)take(98304 * 16);
    uint4* Wh1p = (uint4*)take(98304 * 16);
    u32*  Hb0   = (u32*)take(32 * 1024 * 4);
    u32*  Hb1   = (u32*)take(32 * 1024 * 4);
    float* hstate = (float*)take(32 * 512 * 4);
    float* h1last = (float*)take(32 * 512 * 4);
    u16*  h0seq = (u16*)take((size_t)32 * 2048 * 512 * 2);
    size_t fixed_end = off;

    int Tc = 2048;
    if (ws_size > 0) {
        while (Tc > 128 &&
               fixed_end + (size_t)32 * Tc * 1536 * 2 > ws_size) Tc >>= 1;
    }
    int lgTc = 31 - __builtin_clz((u32)Tc);
    u16* xibuf = (u16*)take((size_t)32 * Tc * 1536 * 2);
    int nChunk = 2048 / Tc;

    // prep
    transpose_cast<<<dim3(48, 8), 256, 0, stream>>>(Wi0, Wi0t, 256, 1536);
    transpose_cast<<<dim3(48, 16), 256, 0, stream>>>(Wi1, Wi1t, 512, 1536);
    pack_wh<<<384, 256, 0, stream>>>(Wh0, Wh0p);
    pack_wh<<<384, 256, 0, stream>>>(Wh1, Wh1p);

    // layer 0
    for (int c = 0; c < nChunk; ++c) {
        int t0 = c * Tc;
        gemm_xi<256, true><<<dim3(24, Tc / 2), 256, 0, stream>>>(
            (const void*)x, Wi0t, bi0, xibuf, t0, lgTc);
        const u16* xi_p = xibuf; const uint4* wh_p = Wh0p; const float* bh_p = bhn0;
        u32* hb_p = Hb0; u16* hs_p = h0seq; float* h1_p = nullptr;
        float* st_p = hstate; int t0v = t0, Tcv = Tc, l0v = 1;
        void* args[] = {&xi_p, &wh_p, &bh_p, &hb_p, &hs_p, &h1_p, &st_p,
                        &t0v, &Tcv, &l0v};
        hipLaunchCooperativeKernel(gru_scan, dim3(64), dim3(512), args, 0, stream);
    }
    // layer 1
    for (int c = 0; c < nChunk; ++c) {
        int t0 = c * Tc;
        gemm_xi<512, false><<<dim3(24, Tc / 2), 256, 0, stream>>>(
            (const void*)h0seq, Wi1t, bi1, xibuf, t0, lgTc);
        const u16* xi_p = xibuf; const uint4* wh_p = Wh1p; const float* bh_p = bhn1;
        u32* hb_p = Hb1; u16* hs_p = nullptr; float* h1_p = h1last;
        float* st_p = hstate; int t0v = t0, Tcv = Tc, l0v = 0;
        void* args[] = {&xi_p, &wh_p, &bh_p, &hb_p, &hs_p, &h1_p, &st_p,
                        &t0v, &Tcv, &l0v};
        hipLaunchCooperativeKernel(gru_scan, dim3(64), dim3(512), args, 0, stream);
    }
    final_fc<<<32, 64, 0, stream>>>(h1last, Wfc, bfc, out);
}

// Round 2
// 6653.846 us; speedup vs baseline: 2.8514x; 2.8514x over previous
//
#include <hip/hip_runtime.h>

// ---------------------------------------------------------------------------
// GRU forecaster: B=32, T=2048, I=256, H=512, L=2, O=64   (f16 datapath)
// Scan: 32 clusters (1 batch each) x 8 member WGs, 576 threads each.
// Member m owns output j in [64m, 64m+64). Inside the WG, COMPUTE WAVE w
// (w=0..7) owns k-chunk [64w, 64w+64) -- which is exactly member w's h output,
// so wave w polls ONLY member w's mailbox (single-producer dependency, no
// per-step __syncthreads). Lane l computes full-chunk dots for j=64m+l
// (no shuffle reduce). Partials land in LDS with release-flags; WAVE 8
// (finalizer, no weights) waits on the 8 flags, sums, activates, publishes
// h as u32 {epoch<<16|f16} agent-scope atomics, prefetches xi.
// ---------------------------------------------------------------------------

typedef unsigned int  u32;
typedef unsigned short u16;
typedef float v4f __attribute__((ext_vector_type(4)));
typedef _Float16 v2h __attribute__((ext_vector_type(2)));
typedef _Float16 v8h __attribute__((ext_vector_type(8)));

#if defined(__has_builtin)
#  if __has_builtin(__builtin_amdgcn_fdot2)
#    define FDOT2(a, b, c) __builtin_amdgcn_fdot2((a), (b), (c), false)
#  endif
#endif
#ifndef FDOT2
#  define FDOT2(a, b, c) ((c) + (float)(a)[0] * (float)(b)[0] + (float)(a)[1] * (float)(b)[1])
#endif

__device__ __forceinline__ u16 f2h(float f) {
    _Float16 h = (_Float16)f;
    return *(u16*)&h;
}
__device__ __forceinline__ float h2f(u16 b) {
    _Float16 h = *(_Float16*)&b;
    return (float)h;
}

// --------------------------- prep kernels ----------------------------------

// src fp32 [R][C] -> dst f16 [C][R]  (32x32 tiles)
__global__ __launch_bounds__(256) void transpose_cast(const float* __restrict__ src,
                                                      u16* __restrict__ dst,
                                                      int R, int C) {
    __shared__ u16 tile[32][33];
    int c0 = blockIdx.x * 32, r0 = blockIdx.y * 32;
    int t = threadIdx.x;
    {
        int rl = t >> 3, cl4 = (t & 7) * 4;
        float4 v = *(const float4*)&src[(size_t)(r0 + rl) * C + c0 + cl4];
        tile[rl][cl4 + 0] = f2h(v.x);
        tile[rl][cl4 + 1] = f2h(v.y);
        tile[rl][cl4 + 2] = f2h(v.z);
        tile[rl][cl4 + 3] = f2h(v.w);
    }
    __syncthreads();
    {
        int cl = t >> 3, rl4 = (t & 7) * 4;
        uint2 o;
        o.x = (u32)tile[rl4 + 0][cl] | ((u32)tile[rl4 + 1][cl] << 16);
        o.y = (u32)tile[rl4 + 2][cl] | ((u32)tile[rl4 + 3][cl] << 16);
        *(uint2*)&dst[(size_t)(c0 + cl) * R + r0 + rl4] = o;
    }
}

// Wh fp32 [512][1536] -> f16 packed for the scan. uint4 index
// ((m*8 + w)*24 + c)*64 + l,  c = g*8+qk. Holds k-pairs
// {Wh[kb+2p][col], Wh[kb+2p+1][col]}, kb = w*64 + qk*8, col = g*512 + m*64 + l.
__global__ __launch_bounds__(256) void pack_wh(const float* __restrict__ Wh,
                                               uint4* __restrict__ dst) {
    int id = blockIdx.x * 256 + threadIdx.x;   // < 98304
    int l = id & 63;
    int c = (id >> 6) % 24;
    int mw = id / 1536;                        // m*8 + w
    int m = mw >> 3, w = mw & 7;
    int g = c >> 3, qk = c & 7;
    int col = g * 512 + m * 64 + l;
    int kb = w * 64 + qk * 8;
    u32 d[4];
#pragma unroll
    for (int p = 0; p < 4; ++p) {
        u16 a = f2h(Wh[(size_t)(kb + 2 * p) * 1536 + col]);
        u16 b = f2h(Wh[(size_t)(kb + 2 * p + 1) * 1536 + col]);
        d[p] = (u32)a | ((u32)b << 16);
    }
    uint4 o; o.x = d[0]; o.y = d[1]; o.z = d[2]; o.w = d[3];
    dst[id] = o;
}

// ---------------- GEMM: xi_chunk = A_rows @ Bt^T + bias -> f16 --------------
template <int K, bool AF32>
__global__ __launch_bounds__(256) void gemm_xi(const void* __restrict__ Ap,
                                               const u16* __restrict__ Bt,
                                               const float* __restrict__ bias,
                                               u16* __restrict__ C,
                                               int t0, int lgTc) {
    __shared__ u16 As[64 * 40];
    __shared__ u16 Bs[64 * 40];
    const int tid = threadIdx.x;
    const int n0 = blockIdx.x * 64;
    const int m0 = blockIdx.y * 64;
    const int row = tid >> 2, koff = (tid & 3) * 8;
    const int lane = tid & 63, w = tid >> 6;
    const int m = m0 + row;
    const int b = m >> lgTc;
    const int tl = m & ((1 << lgTc) - 1);
    const size_t srow = ((size_t)b << 11) + (size_t)(t0 + tl);
    v4f acc[4];
#pragma unroll
    for (int i = 0; i < 4; ++i) acc[i] = (v4f){0.f, 0.f, 0.f, 0.f};

    for (int k0 = 0; k0 < K; k0 += 32) {
        if (AF32) {
            const float* A = (const float*)Ap;
            float4 v0 = *(const float4*)&A[srow * K + k0 + koff];
            float4 v1 = *(const float4*)&A[srow * K + k0 + koff + 4];
            uint4 o;
            o.x = (u32)f2h(v0.x) | ((u32)f2h(v0.y) << 16);
            o.y = (u32)f2h(v0.z) | ((u32)f2h(v0.w) << 16);
            o.z = (u32)f2h(v1.x) | ((u32)f2h(v1.y) << 16);
            o.w = (u32)f2h(v1.z) | ((u32)f2h(v1.w) << 16);
            *(uint4*)&As[row * 40 + koff] = o;
        } else {
            const u16* A = (const u16*)Ap;
            *(uint4*)&As[row * 40 + koff] =
                *(const uint4*)&A[srow * K + k0 + koff];
        }
        *(uint4*)&Bs[row * 40 + koff] =
            *(const uint4*)&Bt[(size_t)(n0 + row) * K + k0 + koff];
        __syncthreads();
        v8h a = *(const v8h*)&As[(w * 16 + (lane & 15)) * 40 + (lane >> 4) * 8];
#pragma unroll
        for (int nt = 0; nt < 4; ++nt) {
            v8h bm = *(const v8h*)&Bs[(nt * 16 + (lane & 15)) * 40 + (lane >> 4) * 8];
            acc[nt] = __builtin_amdgcn_mfma_f32_16x16x32_f16(a, bm, acc[nt], 0, 0, 0);
        }
        __syncthreads();
    }
#pragma unroll
    for (int nt = 0; nt < 4; ++nt) {
        int col = n0 + nt * 16 + (lane & 15);
        float bv = bias[col];
#pragma unroll
        for (int rI = 0; rI < 4; ++rI) {
            int rowm = m0 + w * 16 + (lane >> 4) * 4 + rI;
            C[(size_t)rowm * 1536 + col] = f2h(acc[nt][rI] + bv);
        }
    }
}

// --------------------------- GRU scan (cooperative) -------------------------
// grid = 256 x 576. cluster = wg & 31 (batch), member = wg >> 5 (same XCD).
__global__ __launch_bounds__(576) void gru_scan(const u16* __restrict__ xi,
                                                const uint4* __restrict__ Whp,
                                                const float* __restrict__ bhn,
                                                u32* __restrict__ Hb,
                                                u16* __restrict__ hseq,
                                                float* __restrict__ h1last,
                                                float* __restrict__ hstate,
                                                int t0, int Tc, int layer0) {
    __shared__ __align__(16) u16 Sh[8][64];        // per-wave h-chunk broadcast
    __shared__ float P[2][8][3][64];               // [parity][wave][gate][j-lane]
    __shared__ u32 flagP[2][8];

    const int tid = threadIdx.x;
    const int wg = blockIdx.x;
    const int cluster = wg & 31;          // batch
    const int member = wg >> 5;           // 8 members per cluster, same XCD
    const int W = tid >> 6, lane = tid & 63;
    const int bg = cluster;

    if (tid < 16) ((u32*)flagP)[tid] = 0;

    if (W < 8) {
        // ---------------- compute wave: k-chunk [64W, 64W+64) ----------------
        uint4 Wreg[24];
        {
            const uint4* src = Whp + ((size_t)(member * 8 + W) * 24) * 64 + lane;
#pragma unroll
            for (int c = 0; c < 24; ++c) Wreg[c] = src[c * 64];
        }
        __syncthreads();   // flag init visible before first poll/write

        u32* pollbase = Hb + (size_t)cluster * 1024 + W * 64 + lane;
        for (int t = t0; t < t0 + Tc; ++t) {
            u16 hv = 0;
            if (t > 0) {
                u32* myq = pollbase + ((t - 1) & 1) * 512;
                const u32 target = (u32)(u16)t << 16;
                u32 qv = 0;
                for (int it = 0; it < 4000000; ++it) {
                    qv = __hip_atomic_load(myq, __ATOMIC_RELAXED, __HIP_MEMORY_SCOPE_AGENT);
                    if ((qv & 0xFFFF0000u) == target) break;
                    if (it > 2) __builtin_amdgcn_s_sleep(1);
                }
                hv = (u16)qv;
            }
            Sh[W][lane] = hv;   // within-wave share (lgkmcnt orders write->read)

            float a0 = 0.f, a1 = 0.f, a2 = 0.f;
#pragma unroll
            for (int qk = 0; qk < 8; ++qk) {
                v8h h8 = *(const v8h*)&Sh[W][qk * 8];
                const v2h* hp = (const v2h*)&h8;
                v8h w0 = *(const v8h*)&Wreg[qk];
                v8h w1 = *(const v8h*)&Wreg[8 + qk];
                v8h w2 = *(const v8h*)&Wreg[16 + qk];
                const v2h* p0 = (const v2h*)&w0;
                const v2h* p1 = (const v2h*)&w1;
                const v2h* p2 = (const v2h*)&w2;
#pragma unroll
                for (int p = 0; p < 4; ++p) {
                    a0 = FDOT2(p0[p], hp[p], a0);
                    a1 = FDOT2(p1[p], hp[p], a1);
                    a2 = FDOT2(p2[p], hp[p], a2);
                }
            }
            const int pp = t & 1;
            P[pp][W][0][lane] = a0;
            P[pp][W][1][lane] = a1;
            P[pp][W][2][lane] = a2;
            if (lane == 0)
                __hip_atomic_store(&flagP[pp][W], (u32)(t + 1), __ATOMIC_RELEASE,
                                   __HIP_MEMORY_SCOPE_WORKGROUP);
        }
    } else {
        // ---------------- finalizer wave (W == 8): j = member*64 + lane ------
        const int j = member * 64 + lane;
        float bhnv = bhn[j];
        float hprev = (t0 > 0) ? hstate[bg * 512 + j] : 0.f;
        const u16* xp = xi + (size_t)bg * Tc * 1536 + j;
        u16 rx = xp[0], rz = xp[512], rn = xp[1024];
        __syncthreads();

        u32* slotj = Hb + (size_t)cluster * 1024 + j;
        for (int t = t0; t < t0 + Tc; ++t) {
            const int pp = t & 1;
            // wait for all 8 compute waves' partials of this step
            for (int it = 0; it < 4000000; ++it) {
                u32 v = __hip_atomic_load(&flagP[pp][lane & 7], __ATOMIC_ACQUIRE,
                                          __HIP_MEMORY_SCOPE_WORKGROUP);
                if (__all(v == (u32)(t + 1))) break;
                if (it > 8) __builtin_amdgcn_s_sleep(1);
            }
            float a0 = 0.f, a1 = 0.f, a2 = 0.f;
#pragma unroll
            for (int w = 0; w < 8; ++w) {
                a0 += P[pp][w][0][lane];
                a1 += P[pp][w][1][lane];
                a2 += P[pp][w][2][lane];
            }
            float r = 1.f / (1.f + __expf(-(h2f(rx) + a0)));
            float z = 1.f / (1.f + __expf(-(h2f(rz) + a1)));
            float nx = h2f(rn) + r * (a2 + bhnv);
            float n = 1.f - 2.f / (__expf(2.f * nx) + 1.f);   // tanh
            float hn = (1.f - z) * n + z * hprev;
            hprev = hn;
            u16 hh = f2h(hn);
            __hip_atomic_store(&slotj[pp * 512], ((u32)(u16)(t + 1) << 16) | (u32)hh,
                               __ATOMIC_RELAXED, __HIP_MEMORY_SCOPE_AGENT);
            if (layer0) hseq[((size_t)bg * 2048 + t) * 512 + j] = hh;
            if (!layer0 && t == 2047) h1last[bg * 512 + j] = hn;
            if (t + 1 < t0 + Tc) {   // prefetch xi for t+1
                const u16* p = xi + ((size_t)bg * Tc + (t + 1 - t0)) * 1536 + j;
                rx = p[0]; rz = p[512]; rn = p[1024];
            }
        }
        hstate[bg * 512 + j] = hprev;
    }
}

// --------------------------- final FC --------------------------------------
__global__ __launch_bounds__(64) void final_fc(const float* __restrict__ h1,
                                               const float* __restrict__ Wfc,
                                               const float* __restrict__ bfc,
                                               float* __restrict__ out) {
    int b = blockIdx.x, o = threadIdx.x;
    float acc = bfc[o];
    for (int k = 0; k < 512; ++k) acc += h1[b * 512 + k] * Wfc[k * 64 + o];
    out[b * 64 + o] = acc;
}

// --------------------------- launch ----------------------------------------

extern "C" void kernel_launch(void* const* d_in, const int* in_sizes, int n_in,
                              void* d_out, int out_size, void* d_ws, size_t ws_size,
                              hipStream_t stream) {
    const float* x    = (const float*)d_in[0];
    const float* Wi0  = (const float*)d_in[1];
    const float* bi0  = (const float*)d_in[2];
    const float* Wh0  = (const float*)d_in[3];
    const float* bhn0 = (const float*)d_in[4];
    const float* Wi1  = (const float*)d_in[5];
    const float* bi1  = (const float*)d_in[6];
    const float* Wh1  = (const float*)d_in[7];
    const float* bhn1 = (const float*)d_in[8];
    const float* Wfc  = (const float*)d_in[9];
    const float* bfc  = (const float*)d_in[10];
    float* out = (float*)d_out;
    (void)in_sizes; (void)n_in; (void)out_size;

    char* ws = (char*)d_ws;
    size_t off = 0;
    auto take = [&](size_t bytes) -> char* {
        char* p = ws + off;
        off = (off + bytes + 255) & ~(size_t)255;
        return p;
    };
    u16*  Wi0t  = (u16*)take(1536 * 256 * 2);
    u16*  Wi1t  = (u16*)take(1536 * 512 * 2);
    uint4* Wh0p = (uint4*)take(98304 * 16);
    uint4* Wh1p = (uint4*)take(98304 * 16);
    u32*  Hb0   = (u32*)take(32 * 1024 * 4);
    u32*  Hb1   = (u32*)take(32 * 1024 * 4);
    float* hstate = (float*)take(32 * 512 * 4);
    float* h1last = (float*)take(32 * 512 * 4);
    u16*  h0seq = (u16*)take((size_t)32 * 2048 * 512 * 2);
    size_t fixed_end = off;

    int Tc = 2048;
    if (ws_size > 0) {
        while (Tc > 128 &&
               fixed_end + (size_t)32 * Tc * 1536 * 2 > ws_size) Tc >>= 1;
    }
    int lgTc = 31 - __builtin_clz((u32)Tc);
    u16* xibuf = (u16*)take((size_t)32 * Tc * 1536 * 2);
    int nChunk = 2048 / Tc;

    // prep
    transpose_cast<<<dim3(48, 8), 256, 0, stream>>>(Wi0, Wi0t, 256, 1536);
    transpose_cast<<<dim3(48, 16), 256, 0, stream>>>(Wi1, Wi1t, 512, 1536);
    pack_wh<<<384, 256, 0, stream>>>(Wh0, Wh0p);
    pack_wh<<<384, 256, 0, stream>>>(Wh1, Wh1p);

    // layer 0
    for (int c = 0; c < nChunk; ++c) {
        int t0 = c * Tc;
        gemm_xi<256, true><<<dim3(24, Tc / 2), 256, 0, stream>>>(
            (const void*)x, Wi0t, bi0, xibuf, t0, lgTc);
        const u16* xi_p = xibuf; const uint4* wh_p = Wh0p; const float* bh_p = bhn0;
        u32* hb_p = Hb0; u16* hs_p = h0seq; float* h1_p = nullptr;
        float* st_p = hstate; int t0v = t0, Tcv = Tc, l0v = 1;
        void* args[] = {&xi_p, &wh_p, &bh_p, &hb_p, &hs_p, &h1_p, &st_p,
                        &t0v, &Tcv, &l0v};
        hipLaunchCooperativeKernel(gru_scan, dim3(256), dim3(576), args, 0, stream);
    }
    // layer 1
    for (int c = 0; c < nChunk; ++c) {
        int t0 = c * Tc;
        gemm_xi<512, false><<<dim3(24, Tc / 2), 256, 0, stream>>>(
            (const void*)h0seq, Wi1t, bi1, xibuf, t0, lgTc);
        const u16* xi_p = xibuf; const uint4* wh_p = Wh1p; const float* bh_p = bhn1;
        u32* hb_p = Hb1; u16* hs_p = nullptr; float* h1_p = h1last;
        float* st_p = hstate; int t0v = t0, Tcv = Tc, l0v = 0;
        void* args[] = {&xi_p, &wh_p, &bh_p, &hb_p, &hs_p, &h1_p, &st_p,
                        &t0v, &Tcv, &l0v};
        hipLaunchCooperativeKernel(gru_scan, dim3(256), dim3(576), args, 0, stream);
    }
    final_fc<<<32, 64, 0, stream>>>(h1last, Wfc, bfc, out);
}